// Round 2
// 255.870 us; speedup vs baseline: 1.0140x; 1.0140x over previous
//
#include <hip/hip_runtime.h>
#include <hip/hip_bf16.h>
#include <type_traits>

// ResGatedGraphConv x3 + softmax.
// R10: gather = compiler-tracked loads (correct counted vmcnt for free),
// MLP forced structurally: steady-state batches consume with COMPILE-TIME
// bound 8 (no branches -> nothing for MachineSink to sink into) and
// sched_barrier(0) between the 8-load issue block and the consume block.
// readlane -> uniform SGPR row base (saddr loads, no per-edge 64b VALU).
// R9's inline-asm loads + manual s_waitcnt were miscompiled (consume could
// be placed before the wait at IR/DAG level) -> reverted to compiler loads.
// N=20000 nodes, E=320000 edges, dims 256 -> 256 -> 128 -> 64.

#define NN 20000
#define EE 320000
#define ELLW 64  // max degree slot; Poisson(16) => P(deg>64) ~ 1e-19

typedef _Float16 half8 __attribute__((ext_vector_type(8)));
typedef _Float16 half4 __attribute__((ext_vector_type(4)));
typedef _Float16 half2v __attribute__((ext_vector_type(2)));
typedef float f32x4 __attribute__((ext_vector_type(4)));

__device__ __forceinline__ _Float16 f2h(float f) { return (_Float16)f; }
__device__ __forceinline__ float fsigmoid_mul(float v, float x) {
    // v * sigmoid(x), approx rcp (v_rcp_f32, ~1e-7 rel err)
    return v * __builtin_amdgcn_rcpf(1.f + __expf(-x));
}

// ---------------------------------------------------------------------------
// Weight prep layout (baked into Wt so the GEMM writes final memory order):
// per node row of width 4D: [0,D)=key, [D,3D)=q/v interleaved in DV-groups
// (DV=D/64; group g holds q[g*DV..+DV) then v[g*DV..+DV)), [3D,4D)=skip
// (conv output bias folded into catbias).
struct PrepArgs {
    const float* w[3][4];  // [layer][grp k,q,v,skip]
    const float* b[3][4];  // [layer][grp] (skip slot = conv bias)
    _Float16* wt[3];
    float* cb[3];
};

// K0: blocks [0,79) zero deg | block 79 i64 probe | [80,1744) weight prep |
// [1744,4244) fp32->fp16 cast of x.
__global__ __launch_bounds__(256) void setup_all_kernel(
    const int* __restrict__ ei, int* __restrict__ deg, int* __restrict__ flag,
    const float* __restrict__ x, _Float16* __restrict__ Xh, PrepArgs a) {
    const int b = blockIdx.x;
    const int tid = threadIdx.x;
    if (b < 79) {
        const int i = b * 256 + tid;
        if (i < NN) deg[i] = 0;
    } else if (b == 79) {
        // int64-vs-int32 edge_index probe: if data is int64 (values < 2^31),
        // every odd int32 word is 0 (see R0 notes).
        __shared__ int nz;
        if (tid == 0) nz = 0;
        __syncthreads();
        int c = 0;
        for (int t = tid; t < 1024; t += 256)
            if (ei[2 * t + 1] != 0) c = 1;
        if (c) atomicAdd(&nz, 1);
        __syncthreads();
        if (tid == 0) *flag = (nz == 0) ? 1 : 0;
    } else if (b < 1744) {
        const int idx = (b - 80) * 256 + tid;  // < 425984
        // L1: K=256,D=256 (262144) | L2: K=256,D=128 (131072) | L3: K=128,D=64
        int layer, li, K, D, s;
        if (idx < 262144) {
            layer = 0; li = idx; K = 256; D = 256; s = 2;
        } else if (idx < 393216) {
            layer = 1; li = idx - 262144; K = 256; D = 128; s = 1;
        } else {
            layer = 2; li = idx - 393216; K = 128; D = 64; s = 0;
        }
        const int p = li / K;
        const int k = li - p * K;
        const int DV = D >> 6;
        int grp, c;
        if (p < D) {
            grp = 0; c = p;
        } else if (p < 3 * D) {
            const int t = p - D;
            const int g = t >> (s + 1);
            const int r = t & (2 * DV - 1);
            if (r < DV) { grp = 1; c = g * DV + r; }
            else        { grp = 2; c = g * DV + r - DV; }
        } else {
            grp = 3; c = p - 3 * D;
        }
        a.wt[layer][(size_t)p * K + k] =
            f2h(a.w[layer][grp][(size_t)k * D + c]);
        if (k == 0) a.cb[layer][p] = a.b[layer][grp][c];
    } else {
        const int i = ((b - 1744) * 256 + tid) * 8;
        if (i < NN * 256) {
            const float4 f0 = *(const float4*)(x + i);
            const float4 f1 = *(const float4*)(x + i + 4);
            half8 h;
            h[0] = f2h(f0.x); h[1] = f2h(f0.y); h[2] = f2h(f0.z); h[3] = f2h(f0.w);
            h[4] = f2h(f1.x); h[5] = f2h(f1.y); h[6] = f2h(f1.z); h[7] = f2h(f1.w);
            *(half8*)(Xh + i) = h;
        }
    }
}

// ---------------------------------------------------------------------------
// fp16 MFMA GEMM tile: C = A[M,K] @ Bt[N,K]^T + catbias -> fp16 O[M][N].
// 128x128 tile, BK=32, double-buffered staging, one barrier per K-iter.
// Epilogue transposes each wave's 64x64 tile through a private 4KB LDS zone
// for coalesced half8 stores. Bt columns pre-permuted (see PrepArgs).
__device__ __forceinline__ void gemm_tile(
    int bm, int bn, const _Float16* __restrict__ A,
    const _Float16* __restrict__ Bt, const float* __restrict__ catbias,
    _Float16* __restrict__ O, int M, int K, int N) {
    __shared__ _Float16 As[2][4096];  // [buf][row*32+k], 16 KB
    __shared__ _Float16 Bs[2][4096];

    const int tid = threadIdx.x;
    const int wid = tid >> 6;
    const int lane = tid & 63;
    const int tile_m = bm * 128;
    const int tile_n = bn * 128;
    const int wm = (wid & 1) * 64;
    const int wn = (wid >> 1) * 64;

    const int st_row = (wid << 4) + (lane >> 2);
    const int st_kc = (lane & 3) << 3;

    auto stage = [&](int buf, int kt) {
#pragma unroll
        for (int j = 0; j < 2; ++j) {
            int ar = tile_m + j * 64 + st_row;
            ar = ar < M ? ar : M - 1;  // clamp (stores are guarded)
            const _Float16* ag = A + (size_t)ar * K + kt + st_kc;
            __builtin_amdgcn_global_load_lds(
                (const __attribute__((address_space(1))) unsigned int*)ag,
                (__attribute__((address_space(3))) unsigned int*)
                    &As[buf][j * 2048 + (wid << 9)],
                16, 0, 0);
            const int br = tile_n + j * 64 + st_row;
            const _Float16* bg = Bt + (size_t)br * K + kt + st_kc;
            __builtin_amdgcn_global_load_lds(
                (const __attribute__((address_space(1))) unsigned int*)bg,
                (__attribute__((address_space(3))) unsigned int*)
                    &Bs[buf][j * 2048 + (wid << 9)],
                16, 0, 0);
        }
    };

    stage(0, 0);

    f32x4 acc[4][4] = {};
    const int fr = lane & 15;
    const int fk = (lane >> 4) << 3;
    const int niter = K >> 5;

    for (int it = 0; it < niter; ++it) {
        __syncthreads();  // drains vmcnt -> buf it&1 staged; prev reads done
        if (it + 1 < niter) stage((it + 1) & 1, (it + 1) << 5);
        const _Float16* as = As[it & 1];
        const _Float16* bs = Bs[it & 1];
        half8 af[4], bf[4];
#pragma unroll
        for (int mi = 0; mi < 4; ++mi)
            af[mi] = *(const half8*)&as[(wm + mi * 16 + fr) * 32 + fk];
#pragma unroll
        for (int ni = 0; ni < 4; ++ni)
            bf[ni] = *(const half8*)&bs[(wn + ni * 16 + fr) * 32 + fk];
#pragma unroll
        for (int mi = 0; mi < 4; ++mi)
#pragma unroll
            for (int ni = 0; ni < 4; ++ni)
                acc[mi][ni] = __builtin_amdgcn_mfma_f32_16x16x32_f16(
                    af[mi], bf[ni], acc[mi][ni], 0, 0, 0);
    }
    __syncthreads();  // all ds_reads done before LDS zones are reused

    // epilogue: C/D layout col=lane&15, row=(lane>>4)*4+reg
    _Float16* zone = &As[0][0] + wid * 2048;  // private 4 KB
    const int cl = lane & 15;
    const int rq = (lane >> 4) << 2;
    const int col0 = tile_n + wn;
    const int r0 = tile_m + wm;
#pragma unroll
    for (int mi = 0; mi < 4; ++mi) {
#pragma unroll
        for (int ni = 0; ni < 4; ++ni) {
            const float cb = catbias[col0 + ni * 16 + cl];
#pragma unroll
            for (int r = 0; r < 4; ++r)
                zone[(rq + r) * 72 + ni * 16 + cl] = f2h(acc[mi][ni][r] + cb);
        }
#pragma unroll
        for (int j = 0; j < 2; ++j) {
            const int rr = j * 8 + (lane >> 3);
            const int row = r0 + mi * 16 + rr;
            const half8 v = *(const half8*)&zone[rr * 72 + (lane & 7) * 8];
            if (row < M)
                *(half8*)&O[(size_t)row * N + col0 + (lane & 7) * 8] = v;
        }
    }
}

__global__ __launch_bounds__(256) void gemm_kernel(
    const _Float16* __restrict__ A, const _Float16* __restrict__ Bt,
    const float* __restrict__ catbias, _Float16* __restrict__ O, int M, int K,
    int N, int mblocks) {
    gemm_tile(blockIdx.x % mblocks, blockIdx.x / mblocks, A, Bt, catbias, O, M,
              K, N);
}

// K1: blocks [0,1256) = GEMM layer 1; [1256,2506) = ELL fill (independent).
__global__ __launch_bounds__(256) void gemm1_fill_kernel(
    const _Float16* __restrict__ A, const _Float16* __restrict__ Bt,
    const float* __restrict__ catbias, _Float16* __restrict__ O,
    const int* __restrict__ ei, const int* __restrict__ i64flag,
    int* __restrict__ deg, int* __restrict__ col) {
    if (blockIdx.x < 1256) {
        gemm_tile(blockIdx.x % 157, blockIdx.x / 157, A, Bt, catbias, O, NN,
                  256, 1024);
        return;
    }
    const int e = (blockIdx.x - 1256) * 256 + threadIdx.x;
    if (e >= EE) return;
    int src, dst;
    if (*i64flag) {
        const long long* p = (const long long*)ei;
        src = (int)p[e];
        dst = (int)p[EE + e];
    } else {
        src = ei[e];
        dst = ei[EE + e];
    }
    const int pos = atomicAdd(&deg[dst], 1);
    if (pos < ELLW) col[dst * ELLW + pos] = src;
}

// ---------------------------------------------------------------------------
// Gather aggregation, ELL edges, fp16 [K|QV|S] rows (stride 4D), one wave/node.
// h = S[node] + sum_e sigmoid(K[node]+Q[src]) * V[src]
// R10 scheme: per edge the src row base is wave-uniform -> readlane to SGPR,
// per-lane element index shared by all edges (saddr-form global_load, no
// per-edge 64-bit VALU address math). Double-buffered batches of 8; loads are
// plain C++ (compiler emits precise counted vmcnt per use). Steady-state
// consume uses a COMPILE-TIME trip count of 8 so the issue+consume body is one
// straight-line BB (nothing for MachineSink to sink loads into — R8's
// serialization cause) and sched_barrier(0) keeps the scheduler from
// interleaving consume VALU into the load batch to cut register pressure.
// Lanes >= deg alias the node's own (cache-hot) row; their slots are consumed
// only in the branch-guarded tail, where the guard masks them out.
// MODE 0: write fp16 Hh (next GEMM's A). MODE 1: fused row-softmax -> out.
template <int D, int MODE>
__global__ __launch_bounds__(256, 4) void edge_gather_kernel(
    const int* __restrict__ deg, const int* __restrict__ col,
    const _Float16* __restrict__ KQVS, _Float16* __restrict__ Hh,
    float* __restrict__ out, int n) {
    constexpr int DV = D / 64;
    constexpr int D4 = 4 * D;
    using qv_t = typename std::conditional<
        DV == 4, half8,
        typename std::conditional<DV == 2, half4, half2v>::type>::type;

    const int node = blockIdx.x * 4 + (threadIdx.x >> 6);
    if (node >= n) return;
    const int lane = threadIdx.x & 63;
    const int ld = lane * DV;

    int dg = deg[node];
    dg = dg < ELLW ? dg : ELLW;
    int idx = col[node * ELLW + lane];  // ELL slot 'lane' (garbage if >= dg)
    if (lane >= dg) idx = node;         // safe self-alias, masked in tail

    float k[DV], acc[DV];
    {
        const _Float16* kp = KQVS + (size_t)node * D4 + ld;
        if constexpr (DV == 4) {
            const half4 u = *(const half4*)kp;
#pragma unroll
            for (int j = 0; j < 4; ++j) k[j] = (float)u[j];
        } else if constexpr (DV == 2) {
            const half2v u = *(const half2v*)kp;
            k[0] = (float)u[0]; k[1] = (float)u[1];
        } else {
            k[0] = (float)*kp;
        }
    }
#pragma unroll
    for (int j = 0; j < DV; ++j) acc[j] = 0.f;

    // one edge load: uniform SGPR row base (readlane) + per-lane index
    auto ldqv = [&](qv_t& u, int e) {
        const int s = __builtin_amdgcn_readlane(idx, e);       // uniform
        const qv_t* p = (const qv_t*)(KQVS + (size_t)s * D4 + D) + lane;
        u = *p;
    };
    auto edgeacc = [&](qv_t u) {
#pragma unroll
        for (int j = 0; j < DV; ++j)
            acc[j] += fsigmoid_mul((float)u[DV + j], k[j] + (float)u[j]);
    };

    qv_t ua[8], ub[8];
    auto issue = [&](qv_t* u, int e0) {
#pragma unroll
        for (int j = 0; j < 8; ++j) ldqv(u[j], e0 + j);
    };
    auto consume8 = [&](qv_t* u) {  // branchless: constant trip count
#pragma unroll
        for (int j = 0; j < 8; ++j) edgeacc(u[j]);
    };
    auto consume_tail = [&](qv_t* u, int nb) {
#pragma unroll
        for (int j = 0; j < 8; ++j)
            if (j < nb) edgeacc(u[j]);  // nb wave-uniform -> scalar branch
    };

    if (dg > 0) {
        issue(ua, 0);
        for (int e = 0;;) {
            int nb = dg - e;
            if (nb <= 8) {
                __builtin_amdgcn_sched_barrier(0);
                consume_tail(ua, nb);
                break;
            }
            issue(ub, e + 8);
            __builtin_amdgcn_sched_barrier(0);
            consume8(ua);
            e += 8;
            nb = dg - e;
            if (nb <= 8) {
                __builtin_amdgcn_sched_barrier(0);
                consume_tail(ub, nb);
                break;
            }
            issue(ua, e + 8);
            __builtin_amdgcn_sched_barrier(0);
            consume8(ub);
            e += 8;
        }
    }

    // h = skip (fp16, same row as K) + agg
    float h[DV];
    {
        const _Float16* sp = KQVS + (size_t)node * D4 + 3 * D + ld;
        if constexpr (DV == 4) {
            const half4 u = *(const half4*)sp;
#pragma unroll
            for (int j = 0; j < 4; ++j) h[j] = (float)u[j] + acc[j];
        } else if constexpr (DV == 2) {
            const half2v u = *(const half2v*)sp;
            h[0] = (float)u[0] + acc[0];
            h[1] = (float)u[1] + acc[1];
        } else {
            h[0] = (float)*sp + acc[0];
        }
    }

    if constexpr (MODE == 0) {
        _Float16* op = Hh + (size_t)node * D + ld;
        if constexpr (DV == 4) {
            half4 o;
#pragma unroll
            for (int j = 0; j < 4; ++j) o[j] = f2h(h[j]);
            *(half4*)op = o;
        } else if constexpr (DV == 2) {
            half2v o;
            o[0] = f2h(h[0]); o[1] = f2h(h[1]);
            *(half2v*)op = o;
        } else {
            op[0] = f2h(h[0]);
        }
    } else {
        // fused softmax over the 64-wide row (DV==1: lane owns one value)
        static_assert(MODE == 0 || DV == 1, "softmax fusion needs D==64");
        float m = h[0];
#pragma unroll
        for (int off = 32; off > 0; off >>= 1)
            m = fmaxf(m, __shfl_xor(m, off, 64));
        const float ex = __expf(h[0] - m);
        float sm = ex;
#pragma unroll
        for (int off = 32; off > 0; off >>= 1) sm += __shfl_xor(sm, off, 64);
        out[(size_t)node * 64 + lane] = ex * __builtin_amdgcn_rcpf(sm);
    }
}

// ---------------------------------------------------------------------------
extern "C" void kernel_launch(void* const* d_in, const int* in_sizes, int n_in,
                              void* d_out, int out_size, void* d_ws,
                              size_t ws_size, hipStream_t stream) {
    const float* x = (const float*)d_in[0];
    const int* ei = (const int*)d_in[1];

    char* w = (char*)d_ws;
    _Float16* Xh = (_Float16*)w;     w += (size_t)NN * 256 * 2;
    _Float16* KQVS = (_Float16*)w;   w += (size_t)NN * 1024 * 2;
    _Float16* H1h = (_Float16*)w;    w += (size_t)NN * 256 * 2;
    _Float16* H2h = (_Float16*)w;    w += (size_t)NN * 128 * 2;
    _Float16* Wt1 = (_Float16*)w;    w += (size_t)1024 * 256 * 2;
    _Float16* Wt2 = (_Float16*)w;    w += (size_t)512 * 256 * 2;
    _Float16* Wt3 = (_Float16*)w;    w += (size_t)256 * 128 * 2;
    float* cb1 = (float*)w;          w += 1024 * 4;
    float* cb2 = (float*)w;          w += 512 * 4;
    float* cb3 = (float*)w;          w += 256 * 4;
    int* i64flag = (int*)w;          w += 16;
    int* deg = (int*)w;              w += (size_t)NN * 4;
    int* ell = (int*)w;              w += (size_t)NN * ELLW * 4;

    const dim3 blk(256);
    const int gblocks = (NN + 3) / 4;  // 5000

    PrepArgs pa;
    pa.w[0][0] = (const float*)d_in[2];  pa.b[0][0] = (const float*)d_in[3];
    pa.w[0][1] = (const float*)d_in[4];  pa.b[0][1] = (const float*)d_in[5];
    pa.w[0][2] = (const float*)d_in[6];  pa.b[0][2] = (const float*)d_in[7];
    pa.w[1][0] = (const float*)d_in[8];  pa.b[1][0] = (const float*)d_in[9];
    pa.w[1][1] = (const float*)d_in[10]; pa.b[1][1] = (const float*)d_in[11];
    pa.w[1][2] = (const float*)d_in[12]; pa.b[1][2] = (const float*)d_in[13];
    pa.w[2][0] = (const float*)d_in[14]; pa.b[2][0] = (const float*)d_in[15];
    pa.w[2][1] = (const float*)d_in[16]; pa.b[2][1] = (const float*)d_in[17];
    pa.w[2][2] = (const float*)d_in[18]; pa.b[2][2] = (const float*)d_in[19];
    pa.w[0][3] = (const float*)d_in[20]; pa.b[0][3] = (const float*)d_in[21];
    pa.w[1][3] = (const float*)d_in[22]; pa.b[1][3] = (const float*)d_in[23];
    pa.w[2][3] = (const float*)d_in[24]; pa.b[2][3] = (const float*)d_in[25];
    pa.wt[0] = Wt1; pa.wt[1] = Wt2; pa.wt[2] = Wt3;
    pa.cb[0] = cb1; pa.cb[1] = cb2; pa.cb[2] = cb3;

    // K0: zero deg | i64 probe | weight prep | input cast  (4244 blocks)
    setup_all_kernel<<<4244, blk, 0, stream>>>(ei, deg, i64flag, x, Xh, pa);

    // K1: GEMM layer-1 (1256 blocks) || ELL fill (1250 blocks)
    gemm1_fill_kernel<<<2506, blk, 0, stream>>>(Xh, Wt1, cb1, KQVS, ei,
                                                i64flag, deg, ell);
    edge_gather_kernel<256, 0><<<gblocks, blk, 0, stream>>>(
        deg, ell, KQVS, H1h, nullptr, NN);

    // ---- layer 2: 256 -> 128 ----
    gemm_kernel<<<157 * 4, blk, 0, stream>>>(H1h, Wt2, cb2, KQVS, NN, 256, 512,
                                             157);
    edge_gather_kernel<128, 0><<<gblocks, blk, 0, stream>>>(
        deg, ell, KQVS, H2h, nullptr, NN);

    // ---- layer 3: 128 -> 64, softmax fused into gather ----
    gemm_kernel<<<157 * 2, blk, 0, stream>>>(H2h, Wt3, cb3, KQVS, NN, 128, 256,
                                             157);
    edge_gather_kernel<64, 1><<<gblocks, blk, 0, stream>>>(
        deg, ell, KQVS, nullptr, (float*)d_out, NN);
}